// Round 1
// baseline (70.668 us; speedup 1.0000x reference)
//
#include <hip/hip_runtime.h>
#include <math.h>

#define N_MC 256
#define MAIN_BLOCKS 512
#define NTHR 256
#define MPT 2   // m's per thread: MAIN_BLOCKS*NTHR*MPT == 262144

constexpr float WF        = 2.5f;
constexpr float LOG2PI_F  = 1.8378770664093453f;   // log(2*pi)
constexpr float L2E       = 1.4426950408889634f;   // log2(e)
constexpr float LN2_F     = 0.6931471805599453f;
constexpr float PI_F      = 3.14159265358979323846f;
constexpr float INV_SQRT2 = 0.70710678118654752f;
constexpr float GAMMA_1_5 = 0.8862269254527580f;   // Gamma(1.5)

struct __align__(16) NConst { float tx, B2, P2, pad; };

// ---------------- kernel 1: per-MC-component constants ----------------
__global__ void setup_kernel(const float* __restrict__ k_u,
                             const float* p_sb, const float* p_sn,
                             const float* p_I1, const float* p_I2,
                             NConst* __restrict__ cst) {
    int n = threadIdx.x;
    float sb = *p_sb, sn = *p_sn, I1 = *p_I1, I2 = *p_I2;
    float sn2 = sn * sn;
    float dI  = I2 - I1;
    float ERFW   = erff(WF * INV_SQRT2);
    float I_min  = I1 + 0.5f * dI * (1.0f - ERFW);
    float I_diff = dI * ERFW;

    float tx = k_u[n] * I_diff + I_min;
    float u  = 2.0f * (tx - I1) / dI - 1.0f;
    float ei = erfinvf(u);
    float e2 = ei * ei;

    // log_p_tx(tx)
    float lptx = -logf(2.0f * WF * dI) + 0.5f * LOG2PI_F + e2;
    // G(tx)
    float G = dI * rsqrtf(2.0f * PI_F * sb * sb) * expf(-e2);
    float b = 2.0f * G / sn2;           // z = b * y
    // all n-dependent (and shared constant) parts of log_integrand except
    // b*y, -(x-tx)^2/(2 sn^2), log1p(-exp(-2 b y)), and per-m Q
    float P = lptx
            - 0.5f * logf(G)
            - 0.5f * logf(b)
            - G * G / sn2
            - 2.0f * logf(sn)
            + 0.5f * logf(2.0f / PI_F);

    cst[n].tx = tx;
    cst[n].B2 = b * L2E;   // log2-domain slope for y
    cst[n].P2 = P * L2E;   // log2-domain constant
    cst[n].pad = 0.0f;
}

// ---------------- kernel 2: main MC + mixture loss ----------------
__global__ __launch_bounds__(NTHR) void main_kernel(
        const float* __restrict__ x_g, const float* __restrict__ y_g,
        const float* p_sn, const float* p_I1, const float* p_I2,
        const float* w1, const float* w2, const float* w12,
        const NConst* __restrict__ cst, double* __restrict__ partials,
        int Mv) {

    // ---- wave-uniform scalar setup (cheap, recomputed per thread) ----
    float sn = *p_sn, I1 = *p_I1, I2 = *p_I2;
    float sn2 = sn * sn;
    float inv_sn2 = 1.0f / sn2;
    float dI = I2 - I1;
    float ERFW   = erff(WF * INV_SQRT2);
    float I_diff = dI * ERFW;

    float r0 = *w1, r1 = *w2, r2 = *w12;
    float rm = fmaxf(r0, fmaxf(r1, r2));
    float lse_r = rm + logf(expf(r0 - rm) + expf(r1 - rm) + expf(r2 - rm));
    float lw0 = r0 - lse_r, lw1 = r1 - lse_r, lw2 = r2 - lse_r;

    float base12 = logf(I_diff) - logf((float)N_MC);
    float Qc = -logf(sn) - 0.5f * LOG2PI_F;                      // per-m const of Q
    float K  = logf(2.0f) - logf(GAMMA_1_5) - 4.0f * logf(sn) - 0.5f * LOG2PI_F;
    float c2n = 0.5f * inv_sn2;          // natural-log quadratic coeff
    float nC2 = -c2n * L2E;              // log2-domain, negated

    // ---- stage per-n constants in LDS (read back wave-uniform = broadcast) ----
    __shared__ NConst lcst[N_MC];
    for (int i = threadIdx.x; i < N_MC; i += blockDim.x) lcst[i] = cst[i];
    __syncthreads();

    int tid = blockIdx.x * blockDim.x + threadIdx.x;
    const int stride = MAIN_BLOCKS * NTHR;

    float lx[MPT], lyv[MPT], mx[MPT], sm[MPT];
    bool valid[MPT];
#pragma unroll
    for (int k = 0; k < MPT; ++k) {
        int m = tid + k * stride;
        valid[k] = (m < Mv);
        lx[k]  = valid[k] ? x_g[m] : 0.5f;
        lyv[k] = valid[k] ? y_g[m] : 0.5f;
        mx[k] = -INFINITY;
        sm[k] = 0.0f;
    }

    // ---- inner MC loop: online base-2 logsumexp over n ----
    for (int n = 0; n < N_MC; ++n) {
        NConst c = lcst[n];
#pragma unroll
        for (int k = 0; k < MPT; ++k) {
            float d  = lx[k] - c.tx;
            float t  = c.B2 * lyv[k];                 // z*log2(e)
            float s2 = fmaf(nC2, d * d, c.P2 + t);    // log2-domain score
            float w  = 1.0f - exp2f(-2.0f * t);       // (1 - e^{-2z})
            float m2 = fmaxf(mx[k], s2);
            sm[k] = fmaf(sm[k], exp2f(mx[k] - m2), exp2f(s2 - m2) * w);
            mx[k] = m2;
        }
    }

    // ---- per-m epilogue: mixture LSE, accumulate -log p ----
    double acc = 0.0;
#pragma unroll
    for (int k = 0; k < MPT; ++k) {
        float x = lx[k], y = lyv[k];
        float ly  = logf(y);
        float y2s = y * y * inv_sn2;
        float lp12 = base12 + ly - y2s + Qc + LN2_F * (mx[k] + log2f(sm[k]));
        float d1 = x - I1, d2 = x - I2;
        float base_i = K + 2.0f * ly - y2s;
        float lp1 = base_i - c2n * d1 * d1;
        float lp2 = base_i - c2n * d2 * d2;
        float a0 = lw0 + lp1, a1 = lw1 + lp2, a2 = lw2 + lp12;
        float mm = fmaxf(a0, fmaxf(a1, a2));
        float lp = mm + logf(expf(a0 - mm) + expf(a1 - mm) + expf(a2 - mm));
        if (valid[k]) acc += (double)lp;
    }

    // ---- block reduction (deterministic) ----
    __shared__ double red[NTHR];
    red[threadIdx.x] = acc;
    __syncthreads();
    for (int s = NTHR / 2; s > 0; s >>= 1) {
        if (threadIdx.x < s) red[threadIdx.x] += red[threadIdx.x + s];
        __syncthreads();
    }
    if (threadIdx.x == 0) partials[blockIdx.x] = red[0];
}

// ---------------- kernel 3: final reduction ----------------
__global__ void reduce_kernel(const double* __restrict__ partials, float* __restrict__ out) {
    __shared__ double red[NTHR];
    double a = 0.0;
    for (int i = threadIdx.x; i < MAIN_BLOCKS; i += NTHR) a += partials[i];
    red[threadIdx.x] = a;
    __syncthreads();
    for (int s = NTHR / 2; s > 0; s >>= 1) {
        if (threadIdx.x < s) red[threadIdx.x] += red[threadIdx.x + s];
        __syncthreads();
    }
    if (threadIdx.x == 0) out[0] = (float)(-red[0]);
}

extern "C" void kernel_launch(void* const* d_in, const int* in_sizes, int n_in,
                              void* d_out, int out_size, void* d_ws, size_t ws_size,
                              hipStream_t stream) {
    const float* x   = (const float*)d_in[0];
    const float* y   = (const float*)d_in[1];
    const float* k_u = (const float*)d_in[2];
    const float* sb  = (const float*)d_in[3];
    const float* sn  = (const float*)d_in[4];
    const float* I1  = (const float*)d_in[5];
    const float* I2  = (const float*)d_in[6];
    const float* w1  = (const float*)d_in[7];
    const float* w2  = (const float*)d_in[8];
    const float* w12 = (const float*)d_in[9];
    int Mv = in_sizes[0];

    NConst* cst      = (NConst*)d_ws;
    double* partials = (double*)((char*)d_ws + sizeof(NConst) * N_MC);

    setup_kernel<<<1, N_MC, 0, stream>>>(k_u, sb, sn, I1, I2, cst);
    main_kernel<<<MAIN_BLOCKS, NTHR, 0, stream>>>(x, y, sn, I1, I2, w1, w2, w12,
                                                  cst, partials, Mv);
    reduce_kernel<<<1, NTHR, 0, stream>>>(partials, (float*)d_out);
}

// Round 2
// 49.840 us; speedup vs baseline: 1.4179x; 1.4179x over previous
//
#include <hip/hip_runtime.h>
#include <math.h>

#define N_MC 256
#define MAIN_BLOCKS 512
#define NTHR 256
#define MPT 2   // MAIN_BLOCKS*NTHR*MPT == 262144 == M

constexpr float WF        = 2.5f;
constexpr float LOG2PI_F  = 1.8378770664093453f;   // log(2*pi)
constexpr float L2E       = 1.4426950408889634f;   // log2(e)
constexpr float LN2_F     = 0.6931471805599453f;
constexpr float PI_F      = 3.14159265358979323846f;
constexpr float INV_SQRT2 = 0.70710678118654752f;
constexpr float GAMMA_1_5 = 0.8862269254527580f;   // Gamma(1.5)

// ---------------- kernel 1: per-MC-component constants (log2 domain) -------
// s_log2(n; x,y) = P2p + T2*x + B2*y + nC2*x^2   where nC2 = -L2E/(2 sn^2)
// (expansion of L2E*(P + b*y - (x-tx)^2/(2 sn^2)))
// cst[n] = {P2p, T2, B2, -2*B2}
__global__ void setup_kernel(const float* __restrict__ k_u,
                             const float* p_sb, const float* p_sn,
                             const float* p_I1, const float* p_I2,
                             float4* __restrict__ cst) {
    int n = threadIdx.x;
    float sb = *p_sb, sn = *p_sn, I1 = *p_I1, I2 = *p_I2;
    float sn2 = sn * sn;
    float c2n = 0.5f / sn2;
    float dI  = I2 - I1;
    float ERFW   = erff(WF * INV_SQRT2);
    float I_min  = I1 + 0.5f * dI * (1.0f - ERFW);
    float I_diff = dI * ERFW;

    float tx = k_u[n] * I_diff + I_min;
    float u  = 2.0f * (tx - I1) / dI - 1.0f;
    float ei = erfinvf(u);
    float e2 = ei * ei;

    float lptx = -logf(2.0f * WF * dI) + 0.5f * LOG2PI_F + e2;
    float A = dI * rsqrtf(2.0f * PI_F * sb * sb);
    float G = A * expf(-e2);
    float b = 2.0f * G / sn2;           // z = b * y
    float P = lptx
            - 0.5f * logf(G)
            - 0.5f * logf(b)
            - G * G / sn2
            - 2.0f * logf(sn)
            + 0.5f * logf(2.0f / PI_F);

    float Pp = P - c2n * tx * tx;
    float T  = tx / sn2;                // 2*c2n*tx

    float4 o;
    o.x = Pp * L2E;
    o.y = T  * L2E;
    o.z = b  * L2E;
    o.w = -2.0f * b * L2E;
    cst[n] = o;
}

// ---------------- kernel 2: main MC + mixture loss ----------------
__global__ __launch_bounds__(NTHR) void main_kernel(
        const float* __restrict__ x_g, const float* __restrict__ y_g,
        const float* p_sb, const float* p_sn,
        const float* p_I1, const float* p_I2,
        const float* w1, const float* w2, const float* w12,
        const float4* __restrict__ cst, double* __restrict__ partials,
        int Mv) {

    // ---- wave-uniform scalar setup ----
    float sb = *p_sb, sn = *p_sn, I1 = *p_I1, I2 = *p_I2;
    float sn2 = sn * sn;
    float inv_sn2 = 1.0f / sn2;
    float c2n = 0.5f * inv_sn2;
    float dI = I2 - I1;
    float ERFW   = erff(WF * INV_SQRT2);
    float I_diff = dI * ERFW;
    float A    = dI * rsqrtf(2.0f * PI_F * sb * sb);
    float beta = 2.0f * A * inv_sn2;          // coefficient of g*y in s_nat
    float gmin = expf(-0.5f * WF * WF);
    // CONST0 = -ln(2*WF*dI) - ln A - ln sn + 0.5 ln 2   (see derivation)
    float CONST0 = -logf(2.0f * WF * dI) - logf(A) - logf(sn) + 0.5f * LN2_F;
    float nC2 = -c2n * L2E;                   // log2-domain quadratic coeff

    float r0 = *w1, r1 = *w2, r2 = *w12;
    float rm = fmaxf(r0, fmaxf(r1, r2));
    float lse_r = rm + logf(expf(r0 - rm) + expf(r1 - rm) + expf(r2 - rm));
    float lw0 = r0 - lse_r, lw1 = r1 - lse_r, lw2 = r2 - lse_r;

    float base12 = logf(I_diff) - logf((float)N_MC);
    float Qc = -logf(sn) - 0.5f * LOG2PI_F;
    float K  = logf(2.0f) - logf(GAMMA_1_5) - 4.0f * logf(sn) - 0.5f * LOG2PI_F;

    // ---- stage per-n constants in LDS (broadcast reads, conflict-free) ----
    __shared__ float4 lcst[N_MC];
    for (int i = threadIdx.x; i < N_MC; i += blockDim.x) lcst[i] = cst[i];
    __syncthreads();

    int tid = blockIdx.x * blockDim.x + threadIdx.x;
    const int stride = MAIN_BLOCKS * NTHR;

    float xv[MPT], yv[MPT], D2[MPT], Cl2[MPT], sm[MPT], smc[MPT];
    bool valid[MPT];
#pragma unroll
    for (int k = 0; k < MPT; ++k) {
        int m = tid + k * stride;
        valid[k] = (m < Mv);
        xv[k] = valid[k] ? x_g[m] : 0.5f;
        yv[k] = valid[k] ? y_g[m] : 0.5f;
        // analytic upper bound C on max_n (P + b*y): unimodal in g on [gmin,1]
        float y = yv[k];
        float disc = fmaf(y, y, -4.0f * sn2);
        float root = sqrtf(fmaxf(disc, 0.0f));
        float gs = (y + root) / (2.0f * A);
        gs = fminf(fmaxf(gs, gmin), 1.0f);
        float Ag = A * gs;
        float Cn = CONST0 - 2.0f * logf(gs) - Ag * Ag * inv_sn2 + beta * gs * y;
        Cl2[k] = fmaf(Cn, L2E, 2.0f);         // +2 bits safety margin
        D2[k]  = fmaf(nC2 * xv[k], xv[k], -Cl2[k]);
        sm[k] = 0.0f;
        smc[k] = 0.0f;
    }

    // ---- inner MC loop: fixed-center accumulation, no max tracking ----
#pragma unroll 4
    for (int n = 0; n < N_MC; ++n) {
        float4 c = lcst[n];
#pragma unroll
        for (int k = 0; k < MPT; ++k) {
            float t0 = fmaf(c.y, xv[k], c.x);
            float t1 = fmaf(c.z, yv[k], t0);
            float s  = t1 + D2[k];            // centered log2 score, <= -2
            sm[k]  += exp2f(s);
            float s3 = fmaf(c.w, yv[k], s);   // s - 2*z*log2(e)
            smc[k] += exp2f(s3);
        }
    }

    // ---- per-m epilogue: mixture LSE, accumulate log p ----
    double acc = 0.0;
#pragma unroll
    for (int k = 0; k < MPT; ++k) {
        float x = xv[k], y = yv[k];
        float ly  = logf(y);
        float y2s = y * y * inv_sn2;
        float net = sm[k] - smc[k];           // >= 0.985*sm, no catastrophe
        float lp12 = base12 + ly - y2s + Qc + LN2_F * (Cl2[k] + log2f(net));
        float d1 = x - I1, d2 = x - I2;
        float base_i = K + 2.0f * ly - y2s;
        float lp1 = base_i - c2n * d1 * d1;
        float lp2 = base_i - c2n * d2 * d2;
        float a0 = lw0 + lp1, a1 = lw1 + lp2, a2 = lw2 + lp12;
        float mm = fmaxf(a0, fmaxf(a1, a2));
        float lp = mm + logf(expf(a0 - mm) + expf(a1 - mm) + expf(a2 - mm));
        if (valid[k]) acc += (double)lp;
    }

    // ---- block reduction (deterministic) ----
    __shared__ double red[NTHR];
    red[threadIdx.x] = acc;
    __syncthreads();
    for (int s = NTHR / 2; s > 0; s >>= 1) {
        if (threadIdx.x < s) red[threadIdx.x] += red[threadIdx.x + s];
        __syncthreads();
    }
    if (threadIdx.x == 0) partials[blockIdx.x] = red[0];
}

// ---------------- kernel 3: final reduction ----------------
__global__ void reduce_kernel(const double* __restrict__ partials, float* __restrict__ out) {
    __shared__ double red[NTHR];
    double a = 0.0;
    for (int i = threadIdx.x; i < MAIN_BLOCKS; i += NTHR) a += partials[i];
    red[threadIdx.x] = a;
    __syncthreads();
    for (int s = NTHR / 2; s > 0; s >>= 1) {
        if (threadIdx.x < s) red[threadIdx.x] += red[threadIdx.x + s];
        __syncthreads();
    }
    if (threadIdx.x == 0) out[0] = (float)(-red[0]);
}

extern "C" void kernel_launch(void* const* d_in, const int* in_sizes, int n_in,
                              void* d_out, int out_size, void* d_ws, size_t ws_size,
                              hipStream_t stream) {
    const float* x   = (const float*)d_in[0];
    const float* y   = (const float*)d_in[1];
    const float* k_u = (const float*)d_in[2];
    const float* sb  = (const float*)d_in[3];
    const float* sn  = (const float*)d_in[4];
    const float* I1  = (const float*)d_in[5];
    const float* I2  = (const float*)d_in[6];
    const float* w1  = (const float*)d_in[7];
    const float* w2  = (const float*)d_in[8];
    const float* w12 = (const float*)d_in[9];
    int Mv = in_sizes[0];

    float4* cst      = (float4*)d_ws;
    double* partials = (double*)((char*)d_ws + sizeof(float4) * N_MC);

    setup_kernel<<<1, N_MC, 0, stream>>>(k_u, sb, sn, I1, I2, cst);
    main_kernel<<<MAIN_BLOCKS, NTHR, 0, stream>>>(x, y, sb, sn, I1, I2, w1, w2, w12,
                                                  cst, partials, Mv);
    reduce_kernel<<<1, NTHR, 0, stream>>>(partials, (float*)d_out);
}

// Round 3
// 41.931 us; speedup vs baseline: 1.6853x; 1.1886x over previous
//
#include <hip/hip_runtime.h>
#include <math.h>

#define N_MC 256
#define MAIN_BLOCKS 1024
#define NTHR 256
// MAIN_BLOCKS*NTHR == 262144 == M  (one m per thread)

constexpr float WF        = 2.5f;
constexpr float LOG2PI_F  = 1.8378770664093453f;   // log(2*pi)
constexpr float L2E       = 1.4426950408889634f;   // log2(e)
constexpr float LN2_F     = 0.6931471805599453f;
constexpr float PI_F      = 3.14159265358979323846f;
constexpr float INV_SQRT2 = 0.70710678118654752f;
constexpr float GAMMA_1_5 = 0.8862269254527580f;   // Gamma(1.5)

// ---------------- kernel 1: per-MC-component constants (log2 domain) -------
// s_log2(n; x,y) = Pp2 + T2*x + B2*y + nC2*x^2   (nC2 = -L2E/(2 sn^2))
// cst[n] = {Pp2, T2, B2, pad}
__global__ void setup_kernel(const float* __restrict__ k_u,
                             const float* p_sb, const float* p_sn,
                             const float* p_I1, const float* p_I2,
                             float4* __restrict__ cst) {
    int n = threadIdx.x;
    float sb = *p_sb, sn = *p_sn, I1 = *p_I1, I2 = *p_I2;
    float sn2 = sn * sn;
    float c2n = 0.5f / sn2;
    float dI  = I2 - I1;
    float ERFW   = erff(WF * INV_SQRT2);
    float I_min  = I1 + 0.5f * dI * (1.0f - ERFW);
    float I_diff = dI * ERFW;

    float tx = k_u[n] * I_diff + I_min;
    float u  = 2.0f * (tx - I1) / dI - 1.0f;
    float ei = erfinvf(u);
    float e2 = ei * ei;

    float lptx = -logf(2.0f * WF * dI) + 0.5f * LOG2PI_F + e2;
    float A = dI * rsqrtf(2.0f * PI_F * sb * sb);
    float G = A * expf(-e2);
    float b = 2.0f * G / sn2;           // z = b * y
    float P = lptx
            - 0.5f * logf(G)
            - 0.5f * logf(b)
            - G * G / sn2
            - 2.0f * logf(sn)
            + 0.5f * logf(2.0f / PI_F);

    float Pp = P - c2n * tx * tx;
    float T  = tx / sn2;                // 2*c2n*tx

    float4 o;
    o.x = Pp * L2E;
    o.y = T  * L2E;
    o.z = b  * L2E;
    o.w = 0.0f;
    cst[n] = o;
}

// ---------------- kernel 2: main MC + mixture loss ----------------
__global__ __launch_bounds__(NTHR) void main_kernel(
        const float* __restrict__ x_g, const float* __restrict__ y_g,
        const float* p_sb, const float* p_sn,
        const float* p_I1, const float* p_I2,
        const float* w1, const float* w2, const float* w12,
        const float4* __restrict__ cst, double* __restrict__ partials,
        int Mv) {

    // ---- wave-uniform scalar setup ----
    float sb = *p_sb, sn = *p_sn, I1 = *p_I1, I2 = *p_I2;
    float sn2 = sn * sn;
    float inv_sn2 = 1.0f / sn2;
    float c2n = 0.5f * inv_sn2;
    float dI = I2 - I1;
    float ERFW   = erff(WF * INV_SQRT2);
    float I_diff = dI * ERFW;
    float A    = dI * rsqrtf(2.0f * PI_F * sb * sb);
    float beta = 2.0f * A * inv_sn2;
    float gmin = expf(-0.5f * WF * WF);
    float CONST0 = -logf(2.0f * WF * dI) - logf(A) - logf(sn) + 0.5f * LN2_F;
    float nC2 = -c2n * L2E;

    float r0 = *w1, r1 = *w2, r2 = *w12;
    float rm = fmaxf(r0, fmaxf(r1, r2));
    float lse_r = rm + logf(expf(r0 - rm) + expf(r1 - rm) + expf(r2 - rm));
    float lw0 = r0 - lse_r, lw1 = r1 - lse_r, lw2 = r2 - lse_r;

    float base12 = logf(I_diff) - logf((float)N_MC);
    float Qc = -logf(sn) - 0.5f * LOG2PI_F;
    float K  = logf(2.0f) - logf(GAMMA_1_5) - 4.0f * logf(sn) - 0.5f * LOG2PI_F;

    int m = blockIdx.x * blockDim.x + threadIdx.x;
    bool valid = (m < Mv);
    float xv = valid ? x_g[m] : 0.5f;
    float yv = valid ? y_g[m] : 0.5f;

    // analytic upper bound C on max_n (P + b*y): unimodal in g on [gmin,1]
    float disc = fmaf(yv, yv, -4.0f * sn2);
    float root = sqrtf(fmaxf(disc, 0.0f));
    float gs = (yv + root) / (2.0f * A);
    gs = fminf(fmaxf(gs, gmin), 1.0f);
    float Ag = A * gs;
    float Cn = CONST0 - 2.0f * logf(gs) - Ag * Ag * inv_sn2 + beta * gs * yv;
    float Cl2 = fmaf(Cn, L2E, 2.0f);              // +2 bits safety margin
    float D2  = fmaf(nC2 * xv, xv, -Cl2);         // nC2*x^2 - C

    // ---- inner MC loop: 3 VALU + 1 exp2 + 1 add per n ----
    // constants read wave-uniform -> s_load into SGPRs, no LDS
    float a0 = 0.0f, a1 = 0.0f, a2 = 0.0f, a3 = 0.0f;
#pragma unroll 2
    for (int n = 0; n < N_MC; n += 4) {
        float4 c0 = cst[n + 0];
        float4 c1 = cst[n + 1];
        float4 c2 = cst[n + 2];
        float4 c3 = cst[n + 3];
        a0 += exp2f(fmaf(c0.y, xv, fmaf(c0.z, yv, D2)) + c0.x);
        a1 += exp2f(fmaf(c1.y, xv, fmaf(c1.z, yv, D2)) + c1.x);
        a2 += exp2f(fmaf(c2.y, xv, fmaf(c2.z, yv, D2)) + c2.x);
        a3 += exp2f(fmaf(c3.y, xv, fmaf(c3.z, yv, D2)) + c3.x);
    }
    float sm = (a0 + a1) + (a2 + a3);

    // ---- per-m epilogue: mixture LSE ----
    float ly  = logf(yv);
    float y2s = yv * yv * inv_sn2;
    float lp12 = base12 + ly - y2s + Qc + LN2_F * (Cl2 + log2f(sm));
    float d1 = xv - I1, d2 = xv - I2;
    float base_i = K + 2.0f * ly - y2s;
    float lp1 = base_i - c2n * d1 * d1;
    float lp2 = base_i - c2n * d2 * d2;
    float b0 = lw0 + lp1, b1 = lw1 + lp2, b2 = lw2 + lp12;
    float mm = fmaxf(b0, fmaxf(b1, b2));
    float lp = mm + logf(expf(b0 - mm) + expf(b1 - mm) + expf(b2 - mm));
    double acc = valid ? (double)lp : 0.0;

    // ---- block reduction (deterministic) ----
    __shared__ double red[NTHR];
    red[threadIdx.x] = acc;
    __syncthreads();
    for (int s = NTHR / 2; s > 0; s >>= 1) {
        if (threadIdx.x < s) red[threadIdx.x] += red[threadIdx.x + s];
        __syncthreads();
    }
    if (threadIdx.x == 0) partials[blockIdx.x] = red[0];
}

// ---------------- kernel 3: final reduction ----------------
__global__ void reduce_kernel(const double* __restrict__ partials, float* __restrict__ out) {
    __shared__ double red[NTHR];
    double a = 0.0;
    for (int i = threadIdx.x; i < MAIN_BLOCKS; i += NTHR) a += partials[i];
    red[threadIdx.x] = a;
    __syncthreads();
    for (int s = NTHR / 2; s > 0; s >>= 1) {
        if (threadIdx.x < s) red[threadIdx.x] += red[threadIdx.x + s];
        __syncthreads();
    }
    if (threadIdx.x == 0) out[0] = (float)(-red[0]);
}

extern "C" void kernel_launch(void* const* d_in, const int* in_sizes, int n_in,
                              void* d_out, int out_size, void* d_ws, size_t ws_size,
                              hipStream_t stream) {
    const float* x   = (const float*)d_in[0];
    const float* y   = (const float*)d_in[1];
    const float* k_u = (const float*)d_in[2];
    const float* sb  = (const float*)d_in[3];
    const float* sn  = (const float*)d_in[4];
    const float* I1  = (const float*)d_in[5];
    const float* I2  = (const float*)d_in[6];
    const float* w1  = (const float*)d_in[7];
    const float* w2  = (const float*)d_in[8];
    const float* w12 = (const float*)d_in[9];
    int Mv = in_sizes[0];

    float4* cst      = (float4*)d_ws;
    double* partials = (double*)((char*)d_ws + sizeof(float4) * N_MC);

    setup_kernel<<<1, N_MC, 0, stream>>>(k_u, sb, sn, I1, I2, cst);
    main_kernel<<<MAIN_BLOCKS, NTHR, 0, stream>>>(x, y, sb, sn, I1, I2, w1, w2, w12,
                                                  cst, partials, Mv);
    reduce_kernel<<<1, NTHR, 0, stream>>>(partials, (float*)d_out);
}

// Round 4
// 32.507 us; speedup vs baseline: 2.1739x; 1.2899x over previous
//
#include <hip/hip_runtime.h>
#include <math.h>

#define N_MC 256
#define NTHR 256
#define MPB 128                  // m's per block (2-way n-split)
#define MAIN_BLOCKS 2048         // MPB * MAIN_BLOCKS == 262144 == M

constexpr float WF        = 2.5f;
constexpr float LOG2PI_F  = 1.8378770664093453f;   // log(2*pi)
constexpr float L2E       = 1.4426950408889634f;   // log2(e)
constexpr float LN2_F     = 0.6931471805599453f;
constexpr float PI_F      = 3.14159265358979323846f;
constexpr float INV_SQRT2 = 0.70710678118654752f;
constexpr float GAMMA_1_5 = 0.8862269254527580f;   // Gamma(1.5)

// ---------------- fused main kernel ----------------
// s_log2(n; x,y) = Pp2 + T2*x + B2*y + nC2*x^2   (nC2 = -L2E/(2 sn^2))
__global__ __launch_bounds__(NTHR, 8) void main_kernel(
        const float* __restrict__ x_g, const float* __restrict__ y_g,
        const float* __restrict__ k_u,
        const float* p_sb, const float* p_sn,
        const float* p_I1, const float* p_I2,
        const float* w1, const float* w2, const float* w12,
        double* __restrict__ partials, int Mv) {

    // ---- wave-uniform scalar setup ----
    float sb = *p_sb, sn = *p_sn, I1 = *p_I1, I2 = *p_I2;
    float sn2 = sn * sn;
    float inv_sn2 = 1.0f / sn2;
    float c2n = 0.5f * inv_sn2;
    float dI = I2 - I1;
    float ERFW   = erff(WF * INV_SQRT2);
    float I_min  = I1 + 0.5f * dI * (1.0f - ERFW);
    float I_diff = dI * ERFW;
    float A    = dI * rsqrtf(2.0f * PI_F * sb * sb);
    float beta = 2.0f * A * inv_sn2;
    float gmin = expf(-0.5f * WF * WF);
    float CONST0 = -logf(2.0f * WF * dI) - logf(A) - logf(sn) + 0.5f * LN2_F;
    float nC2 = -c2n * L2E;

    // ---- fused per-n constants into LDS (thread t computes n = t) ----
    __shared__ float4 lcst[N_MC];
    {
        int n = threadIdx.x;          // NTHR == N_MC
        float tx = k_u[n] * I_diff + I_min;
        float u  = 2.0f * (tx - I1) / dI - 1.0f;
        float ei = erfinvf(u);
        float e2 = ei * ei;
        float lptx = -logf(2.0f * WF * dI) + 0.5f * LOG2PI_F + e2;
        float G = A * expf(-e2);
        float b = 2.0f * G / sn2;     // z = b*y
        float P = lptx
                - 0.5f * logf(G)
                - 0.5f * logf(b)
                - G * G / sn2
                - 2.0f * logf(sn)
                + 0.5f * logf(2.0f / PI_F);
        float Pp = P - c2n * tx * tx;
        float T  = tx / sn2;
        float4 o;
        o.x = Pp * L2E;
        o.y = T  * L2E;
        o.z = b  * L2E;
        o.w = 0.0f;
        lcst[n] = o;
    }
    __syncthreads();

    float r0 = *w1, r1 = *w2, r2 = *w12;
    float rm = fmaxf(r0, fmaxf(r1, r2));
    float lse_r = rm + logf(expf(r0 - rm) + expf(r1 - rm) + expf(r2 - rm));
    float lw0 = r0 - lse_r, lw1 = r1 - lse_r, lw2 = r2 - lse_r;

    float base12 = logf(I_diff) - logf((float)N_MC);
    float Qc = -logf(sn) - 0.5f * LOG2PI_F;
    float K  = logf(2.0f) - logf(GAMMA_1_5) - 4.0f * logf(sn) - 0.5f * LOG2PI_F;

    // ---- thread -> (m, n-half) mapping ----
    int t    = threadIdx.x;
    int mi   = t & (MPB - 1);         // m within block
    int half = t >> 7;                // 0 or 1 (waves 0-1 = half0, 2-3 = half1)
    int m    = blockIdx.x * MPB + mi;
    bool valid = (m < Mv);
    float xv = valid ? x_g[m] : 0.5f;
    float yv = valid ? y_g[m] : 0.5f;

    // analytic upper bound C on max_n (P + b*y): unimodal in g on [gmin,1]
    // identical for both halves (depends only on m)
    float disc = fmaf(yv, yv, -4.0f * sn2);
    float root = sqrtf(fmaxf(disc, 0.0f));
    float gs = (yv + root) / (2.0f * A);
    gs = fminf(fmaxf(gs, gmin), 1.0f);
    float Ag = A * gs;
    float Cn = CONST0 - 2.0f * logf(gs) - Ag * Ag * inv_sn2 + beta * gs * yv;
    float Cl2 = fmaf(Cn, L2E, 2.0f);              // +2 bits safety margin
    float D2  = fmaf(nC2 * xv, xv, -Cl2);         // nC2*x^2 - C

    // ---- inner MC half-loop: 128 n's, 3 VALU + 1 exp2 + 1 add per n ----
    float a0 = 0.0f, a1 = 0.0f, a2 = 0.0f, a3 = 0.0f;
    int n0 = half << 7;
#pragma unroll 2
    for (int n = n0; n < n0 + 128; n += 4) {
        float4 c0 = lcst[n + 0];
        float4 c1 = lcst[n + 1];
        float4 c2 = lcst[n + 2];
        float4 c3 = lcst[n + 3];
        a0 += exp2f(fmaf(c0.y, xv, fmaf(c0.z, yv, D2)) + c0.x);
        a1 += exp2f(fmaf(c1.y, xv, fmaf(c1.z, yv, D2)) + c1.x);
        a2 += exp2f(fmaf(c2.y, xv, fmaf(c2.z, yv, D2)) + c2.x);
        a3 += exp2f(fmaf(c3.y, xv, fmaf(c3.z, yv, D2)) + c3.x);
    }
    float sm = (a0 + a1) + (a2 + a3);

    // ---- combine the two n-halves (same center C) ----
    __shared__ float smx[MPB];
    if (half == 1) smx[mi] = sm;
    __syncthreads();

    double acc = 0.0;
    if (half == 0) {
        sm += smx[mi];
        float ly  = logf(yv);
        float y2s = yv * yv * inv_sn2;
        float lp12 = base12 + ly - y2s + Qc + LN2_F * (Cl2 + log2f(sm));
        float d1 = xv - I1, d2 = xv - I2;
        float base_i = K + 2.0f * ly - y2s;
        float lp1 = base_i - c2n * d1 * d1;
        float lp2 = base_i - c2n * d2 * d2;
        float b0 = lw0 + lp1, b1 = lw1 + lp2, b2 = lw2 + lp12;
        float mm = fmaxf(b0, fmaxf(b1, b2));
        float lp = mm + logf(expf(b0 - mm) + expf(b1 - mm) + expf(b2 - mm));
        if (valid) acc = (double)lp;
    }

    // ---- block reduction (deterministic) ----
    __shared__ double red[NTHR];
    red[threadIdx.x] = acc;
    __syncthreads();
    for (int s = NTHR / 2; s > 0; s >>= 1) {
        if (threadIdx.x < s) red[threadIdx.x] += red[threadIdx.x + s];
        __syncthreads();
    }
    if (threadIdx.x == 0) partials[blockIdx.x] = red[0];
}

// ---------------- final reduction ----------------
__global__ void reduce_kernel(const double* __restrict__ partials, float* __restrict__ out) {
    __shared__ double red[NTHR];
    double a = 0.0;
    for (int i = threadIdx.x; i < MAIN_BLOCKS; i += NTHR) a += partials[i];
    red[threadIdx.x] = a;
    __syncthreads();
    for (int s = NTHR / 2; s > 0; s >>= 1) {
        if (threadIdx.x < s) red[threadIdx.x] += red[threadIdx.x + s];
        __syncthreads();
    }
    if (threadIdx.x == 0) out[0] = (float)(-red[0]);
}

extern "C" void kernel_launch(void* const* d_in, const int* in_sizes, int n_in,
                              void* d_out, int out_size, void* d_ws, size_t ws_size,
                              hipStream_t stream) {
    const float* x   = (const float*)d_in[0];
    const float* y   = (const float*)d_in[1];
    const float* k_u = (const float*)d_in[2];
    const float* sb  = (const float*)d_in[3];
    const float* sn  = (const float*)d_in[4];
    const float* I1  = (const float*)d_in[5];
    const float* I2  = (const float*)d_in[6];
    const float* w1  = (const float*)d_in[7];
    const float* w2  = (const float*)d_in[8];
    const float* w12 = (const float*)d_in[9];
    int Mv = in_sizes[0];

    double* partials = (double*)d_ws;

    main_kernel<<<MAIN_BLOCKS, NTHR, 0, stream>>>(x, y, k_u, sb, sn, I1, I2,
                                                  w1, w2, w12, partials, Mv);
    reduce_kernel<<<1, NTHR, 0, stream>>>(partials, (float*)d_out);
}

// Round 5
// 30.717 us; speedup vs baseline: 2.3006x; 1.0583x over previous
//
#include <hip/hip_runtime.h>
#include <math.h>

#define N_MC 256
#define NTHR 256
#define MPB 128                  // m's per block (2-way n-split)
#define MAIN_BLOCKS 2048         // MPB * MAIN_BLOCKS == 262144 == M

constexpr float WF        = 2.5f;
constexpr float LOG2PI_F  = 1.8378770664093453f;   // log(2*pi)
constexpr float L2E       = 1.4426950408889634f;   // log2(e)
constexpr float LN2_F     = 0.6931471805599453f;
constexpr float PI_F      = 3.14159265358979323846f;
constexpr float INV_SQRT2 = 0.70710678118654752f;
constexpr float GAMMA_1_5 = 0.8862269254527580f;   // Gamma(1.5)
constexpr float ERFW_C    = 0.98758066934f;        // erf(WF/sqrt(2)), WF=2.5
constexpr float GMIN_C    = 0.04393693362f;        // exp(-WF^2/2)

__device__ __forceinline__ float fexp2(float x) { return __builtin_amdgcn_exp2f(x); }
__device__ __forceinline__ float flog2(float x) { return __builtin_amdgcn_logf(x); }

// ---------------- kernel 1: per-MC-component constants (log2 domain) -------
// s_log2(n; x,y) = Pp2 + T2*x + B2*y + nC2*x^2   (nC2 = -L2E/(2 sn^2))
__global__ void setup_kernel(const float* __restrict__ k_u,
                             const float* p_sb, const float* p_sn,
                             const float* p_I1, const float* p_I2,
                             float4* __restrict__ cst) {
    int n = threadIdx.x;
    float sb = *p_sb, sn = *p_sn, I1 = *p_I1, I2 = *p_I2;
    float sn2 = sn * sn;
    float c2n = 0.5f / sn2;
    float dI  = I2 - I1;
    float I_min  = I1 + 0.5f * dI * (1.0f - ERFW_C);
    float I_diff = dI * ERFW_C;

    float tx = k_u[n] * I_diff + I_min;
    float u  = 2.0f * (tx - I1) / dI - 1.0f;
    float ei = erfinvf(u);
    float e2 = ei * ei;

    float lptx = -logf(2.0f * WF * dI) + 0.5f * LOG2PI_F + e2;
    float A = dI * rsqrtf(2.0f * PI_F * sb * sb);
    float G = A * expf(-e2);
    float b = 2.0f * G / sn2;           // z = b*y
    float P = lptx
            - 0.5f * logf(G)
            - 0.5f * logf(b)
            - G * G / sn2
            - 2.0f * logf(sn)
            + 0.5f * logf(2.0f / PI_F);

    float Pp = P - c2n * tx * tx;
    float T  = tx / sn2;

    float4 o;
    o.x = Pp * L2E;
    o.y = T  * L2E;
    o.z = b  * L2E;
    o.w = 0.0f;
    cst[n] = o;
}

// ---------------- kernel 2: main MC + mixture loss ----------------
__global__ __launch_bounds__(NTHR, 8) void main_kernel(
        const float* __restrict__ x_g, const float* __restrict__ y_g,
        const float* p_sb, const float* p_sn,
        const float* p_I1, const float* p_I2,
        const float* w1, const float* w2, const float* w12,
        const float4* __restrict__ cst, double* __restrict__ partials,
        int Mv) {

    // ---- stage per-n constants in LDS (one float4 per thread) ----
    __shared__ float4 lcst[N_MC];
    lcst[threadIdx.x] = cst[threadIdx.x];        // NTHR == N_MC

    // ---- wave-uniform scalar setup (raw-log versions) ----
    float sb = *p_sb, sn = *p_sn, I1 = *p_I1, I2 = *p_I2;
    float sn2 = sn * sn;
    float inv_sn2 = 1.0f / sn2;
    float c2n = 0.5f * inv_sn2;
    float dI = I2 - I1;
    float I_diff = dI * ERFW_C;
    float A    = dI * rsqrtf(2.0f * PI_F * sb * sb);
    float beta = 2.0f * A * inv_sn2;
    float ln_sn = flog2(sn) * LN2_F;
    float CONST0 = -flog2(2.0f * WF * dI) * LN2_F - flog2(A) * LN2_F - ln_sn + 0.5f * LN2_F;
    float nC2 = -c2n * L2E;

    float r0 = *w1, r1 = *w2, r2 = *w12;
    float rm = fmaxf(r0, fmaxf(r1, r2));
    float lse_r = rm + LN2_F * flog2(fexp2((r0 - rm) * L2E) + fexp2((r1 - rm) * L2E)
                                     + fexp2((r2 - rm) * L2E));
    float lw0 = r0 - lse_r, lw1 = r1 - lse_r, lw2 = r2 - lse_r;

    float base12 = flog2(I_diff) * LN2_F - flog2((float)N_MC) * LN2_F;
    float Qc = -ln_sn - 0.5f * LOG2PI_F;
    float K  = LN2_F - flog2(GAMMA_1_5) * LN2_F - 4.0f * ln_sn - 0.5f * LOG2PI_F;

    // ---- thread -> (m, n-half) mapping ----
    int t    = threadIdx.x;
    int mi   = t & (MPB - 1);
    int half = t >> 7;                // waves 0-1: half 0, waves 2-3: half 1
    int m    = blockIdx.x * MPB + mi;
    bool valid = (m < Mv);
    float xv = valid ? x_g[m] : 0.5f;
    float yv = valid ? y_g[m] : 0.5f;

    // analytic upper bound C on max_n (P + b*y): unimodal in g on [gmin,1]
    float disc = fmaf(yv, yv, -4.0f * sn2);
    float root = sqrtf(fmaxf(disc, 0.0f));
    float gs = (yv + root) / (2.0f * A);
    gs = fminf(fmaxf(gs, GMIN_C), 1.0f);
    float Ag = A * gs;
    float Cn = CONST0 - 2.0f * flog2(gs) * LN2_F - Ag * Ag * inv_sn2 + beta * gs * yv;
    float Cl2 = fmaf(Cn, L2E, 2.0f);              // +2 bits safety margin
    float D2  = fmaf(nC2 * xv, xv, -Cl2);         // nC2*x^2 - C

    __syncthreads();                              // lcst ready

    // ---- inner MC half-loop: 128 n's; 2 fma + 1 add + 1 raw exp2 + 1 add ----
    float a0 = 0.0f, a1 = 0.0f, a2 = 0.0f, a3 = 0.0f;
    const int n0 = half << 7;
#pragma unroll 4
    for (int n = n0; n < n0 + 128; n += 4) {
        float4 c0 = lcst[n + 0];
        float4 c1 = lcst[n + 1];
        float4 c2 = lcst[n + 2];
        float4 c3 = lcst[n + 3];
        a0 += fexp2(fmaf(c0.y, xv, fmaf(c0.z, yv, D2)) + c0.x);
        a1 += fexp2(fmaf(c1.y, xv, fmaf(c1.z, yv, D2)) + c1.x);
        a2 += fexp2(fmaf(c2.y, xv, fmaf(c2.z, yv, D2)) + c2.x);
        a3 += fexp2(fmaf(c3.y, xv, fmaf(c3.z, yv, D2)) + c3.x);
    }
    float sm = (a0 + a1) + (a2 + a3);

    // ---- combine the two n-halves (same center C) ----
    __shared__ float smx[MPB];
    __shared__ double sred[2];
    if (half) smx[mi] = sm;
    __syncthreads();

    if (!half) {
        sm += smx[mi];
        float ly2 = flog2(yv);
        float ly  = ly2 * LN2_F;
        float y2s = yv * yv * inv_sn2;
        float lp12 = base12 + ly - y2s + Qc + LN2_F * (Cl2 + flog2(sm));
        float d1 = xv - I1, d2 = xv - I2;
        float base_i = K + 2.0f * ly - y2s;
        float lp1 = base_i - c2n * d1 * d1;
        float lp2 = base_i - c2n * d2 * d2;
        float b0 = lw0 + lp1, b1 = lw1 + lp2, b2 = lw2 + lp12;
        float mm = fmaxf(b0, fmaxf(b1, b2));
        float lp = mm + LN2_F * flog2(fexp2((b0 - mm) * L2E) + fexp2((b1 - mm) * L2E)
                                      + fexp2((b2 - mm) * L2E));
        double lpd = valid ? (double)lp : 0.0;
        // wave butterfly (waves 0 and 1 fully active here)
#pragma unroll
        for (int o = 32; o > 0; o >>= 1) lpd += __shfl_xor(lpd, o, 64);
        if ((t & 63) == 0) sred[t >> 6] = lpd;
    }
    __syncthreads();
    if (t == 0) partials[blockIdx.x] = sred[0] + sred[1];
}

// ---------------- final reduction ----------------
__global__ void reduce_kernel(const double* __restrict__ partials, float* __restrict__ out) {
    __shared__ double red[NTHR];
    double a = 0.0;
    for (int i = threadIdx.x; i < MAIN_BLOCKS; i += NTHR) a += partials[i];
    red[threadIdx.x] = a;
    __syncthreads();
    for (int s = NTHR / 2; s > 0; s >>= 1) {
        if (threadIdx.x < s) red[threadIdx.x] += red[threadIdx.x + s];
        __syncthreads();
    }
    if (threadIdx.x == 0) out[0] = (float)(-red[0]);
}

extern "C" void kernel_launch(void* const* d_in, const int* in_sizes, int n_in,
                              void* d_out, int out_size, void* d_ws, size_t ws_size,
                              hipStream_t stream) {
    const float* x   = (const float*)d_in[0];
    const float* y   = (const float*)d_in[1];
    const float* k_u = (const float*)d_in[2];
    const float* sb  = (const float*)d_in[3];
    const float* sn  = (const float*)d_in[4];
    const float* I1  = (const float*)d_in[5];
    const float* I2  = (const float*)d_in[6];
    const float* w1  = (const float*)d_in[7];
    const float* w2  = (const float*)d_in[8];
    const float* w12 = (const float*)d_in[9];
    int Mv = in_sizes[0];

    float4* cst      = (float4*)d_ws;
    double* partials = (double*)((char*)d_ws + sizeof(float4) * N_MC);

    setup_kernel<<<1, N_MC, 0, stream>>>(k_u, sb, sn, I1, I2, cst);
    main_kernel<<<MAIN_BLOCKS, NTHR, 0, stream>>>(x, y, sb, sn, I1, I2, w1, w2, w12,
                                                  cst, partials, Mv);
    reduce_kernel<<<1, NTHR, 0, stream>>>(partials, (float*)d_out);
}

// Round 6
// 25.487 us; speedup vs baseline: 2.7727x; 1.2052x over previous
//
#include <hip/hip_runtime.h>
#include <math.h>

#define N_MC 256
#define NTHR_PREP 256
#define PREP_BLOCKS 1024       // 1024*256 == 262144 == M
#define CB 512                 // main block threads (8 waves)
#define MPB 256                // m's per main block
#define MAIN_BLOCKS 1024       // MPB * MAIN_BLOCKS == 262144
#define NSLICE 32              // n's per wave (8 waves * 32 = 256)

constexpr float WF        = 2.5f;
constexpr float LOG2PI_F  = 1.8378770664093453f;   // log(2*pi)
constexpr float L2E       = 1.4426950408889634f;   // log2(e)
constexpr float LN2_F     = 0.6931471805599453f;
constexpr float PI_F      = 3.14159265358979323846f;
constexpr float GAMMA_1_5 = 0.8862269254527580f;   // Gamma(1.5)
constexpr float ERFW_C    = 0.98758066934f;        // erf(2.5/sqrt(2))
constexpr float GMIN_C    = 0.04393693362f;        // exp(-2.5^2/2)

__device__ __forceinline__ float fexp2(float x) { return __builtin_amdgcn_exp2f(x); }
__device__ __forceinline__ float flog2(float x) { return __builtin_amdgcn_logf(x); }

// ---------------- prep: per-m record {x, y, D2, Cl2} + per-n constants -----
__global__ __launch_bounds__(NTHR_PREP) void prep_kernel(
        const float* __restrict__ x_g, const float* __restrict__ y_g,
        const float* __restrict__ k_u,
        const float* p_sb, const float* p_sn,
        const float* p_I1, const float* p_I2,
        float4* __restrict__ rec,
        float* __restrict__ nPp, float* __restrict__ nT, float* __restrict__ nB,
        int Mv) {
    float sb = *p_sb, sn = *p_sn, I1 = *p_I1, I2 = *p_I2;
    float sn2 = sn * sn, inv_sn2 = 1.0f / sn2, c2n = 0.5f * inv_sn2;
    float dI = I2 - I1;
    float I_diff = dI * ERFW_C;
    float I_min  = I1 + 0.5f * dI * (1.0f - ERFW_C);
    float A    = dI * rsqrtf(2.0f * PI_F * sb * sb);
    float beta = 2.0f * A * inv_sn2;
    float CONST0 = -logf(2.0f * WF * dI) - logf(A) - logf(sn) + 0.5f * LN2_F;
    float nC2 = -c2n * L2E;

    int tid = threadIdx.x;
    if (blockIdx.x == 0) {
        // per-n constants (log2 domain): s = Pp + T*x + B*y + nC2*x^2
        float tx = k_u[tid] * I_diff + I_min;
        float u  = 2.0f * (tx - I1) / dI - 1.0f;
        float ei = erfinvf(u);
        float e2 = ei * ei;
        float lptx = -logf(2.0f * WF * dI) + 0.5f * LOG2PI_F + e2;
        float G = A * expf(-e2);
        float b = 2.0f * G / sn2;       // z = b*y
        float P = lptx - 0.5f * logf(G) - 0.5f * logf(b) - G * G / sn2
                - 2.0f * logf(sn) + 0.5f * logf(2.0f / PI_F);
        nPp[tid] = (P - c2n * tx * tx) * L2E;
        nT[tid]  = (tx * inv_sn2) * L2E;
        nB[tid]  = b * L2E;
    }

    int m = blockIdx.x * NTHR_PREP + tid;
    float4 o;
    if (m < Mv) {
        float xv = x_g[m], yv = y_g[m];
        // analytic upper bound C on max_n (P + b*y): unimodal in g on [gmin,1]
        float disc = fmaf(yv, yv, -4.0f * sn2);
        float root = sqrtf(fmaxf(disc, 0.0f));
        float gs = (yv + root) / (2.0f * A);
        gs = fminf(fmaxf(gs, GMIN_C), 1.0f);
        float Ag = A * gs;
        float Cn = CONST0 - 2.0f * flog2(gs) * LN2_F - Ag * Ag * inv_sn2
                 + beta * gs * yv;
        float Cl2 = fmaf(Cn, L2E, 2.0f);          // +2 bits safety margin
        float D2  = fmaf(nC2 * xv, xv, -Cl2);     // nC2*x^2 - C
        o = make_float4(xv, yv, D2, Cl2);
    } else {
        o = make_float4(0.5f, 0.5f, -20000.0f, 0.0f);  // exp2 -> 0
    }
    rec[m] = o;
}

// ---------------- main: 8-wave n-split, MPT=4, SoA LDS constants ----------
#define PAIR4(Pj, Tj, Bj)                                            \
    a0 += fexp2(fmaf(Tj, x0, fmaf(Bj, y0, d0)) + Pj);                \
    a1 += fexp2(fmaf(Tj, x1, fmaf(Bj, y1, d1)) + Pj);                \
    a2 += fexp2(fmaf(Tj, x2, fmaf(Bj, y2, d2)) + Pj);                \
    a3 += fexp2(fmaf(Tj, x3, fmaf(Bj, y3, d3)) + Pj);

__global__ __launch_bounds__(CB, 8) void main_kernel(
        const float4* __restrict__ rec,
        const float* __restrict__ nPp, const float* __restrict__ nT,
        const float* __restrict__ nB,
        const float* p_sn, const float* p_I1, const float* p_I2,
        const float* w1, const float* w2, const float* w12,
        double* __restrict__ partials, int Mv) {

    __shared__ float sPp[N_MC], sT[N_MC], sB[N_MC];
    __shared__ float part[8][MPB];
    __shared__ double sred[4];

    int tid  = threadIdx.x;
    int wv   = tid >> 6;
    int lane = tid & 63;
    int mb   = blockIdx.x * MPB;

    if (tid < N_MC) { sPp[tid] = nPp[tid]; sT[tid] = nT[tid]; sB[tid] = nB[tid]; }

    // load this thread's 4 m-records (each wave covers all 256 m's)
    float4 r0v = rec[mb + lane];
    float4 r1v = rec[mb + 64 + lane];
    float4 r2v = rec[mb + 128 + lane];
    float4 r3v = rec[mb + 192 + lane];
    float x0 = r0v.x, y0 = r0v.y, d0 = r0v.z;
    float x1 = r1v.x, y1 = r1v.y, d1 = r1v.z;
    float x2 = r2v.x, y2 = r2v.y, d2 = r2v.z;
    float x3 = r3v.x, y3 = r3v.y, d3 = r3v.z;

    // epilogue scalars (overlap with loads)
    float sn = *p_sn, I1 = *p_I1, I2 = *p_I2;
    float sn2 = sn * sn, inv_sn2 = 1.0f / sn2, c2n = 0.5f * inv_sn2;
    float dI = I2 - I1;
    float I_diff = dI * ERFW_C;
    float ln_sn = flog2(sn) * LN2_F;
    float rr0 = *w1, rr1 = *w2, rr2 = *w12;
    float rm = fmaxf(rr0, fmaxf(rr1, rr2));
    float lse_r = rm + LN2_F * flog2(fexp2((rr0 - rm) * L2E)
                 + fexp2((rr1 - rm) * L2E) + fexp2((rr2 - rm) * L2E));
    float lw0 = rr0 - lse_r, lw1 = rr1 - lse_r, lw2 = rr2 - lse_r;
    float base12 = flog2(I_diff) * LN2_F - 8.0f * LN2_F;   // log(I_diff) - log 256
    float Qc = -ln_sn - 0.5f * LOG2PI_F;
    float K  = LN2_F - flog2(GAMMA_1_5) * LN2_F - 4.0f * ln_sn - 0.5f * LOG2PI_F;

    __syncthreads();

    const float4* P4 = (const float4*)sPp;
    const float4* T4 = (const float4*)sT;
    const float4* B4 = (const float4*)sB;
    int g0 = wv * (NSLICE / 4);

    float a0 = 0.0f, a1 = 0.0f, a2 = 0.0f, a3 = 0.0f;
#pragma unroll
    for (int g = 0; g < NSLICE / 4; ++g) {
        float4 P = P4[g0 + g];
        float4 T = T4[g0 + g];
        float4 B = B4[g0 + g];
        PAIR4(P.x, T.x, B.x)
        PAIR4(P.y, T.y, B.y)
        PAIR4(P.z, T.z, B.z)
        PAIR4(P.w, T.w, B.w)
    }

    part[wv][lane]       = a0;
    part[wv][lane + 64]  = a1;
    part[wv][lane + 128] = a2;
    part[wv][lane + 192] = a3;
    __syncthreads();

    if (tid < MPB) {
        int mi = tid;
        float sm = 0.0f;
#pragma unroll
        for (int w = 0; w < 8; ++w) sm += part[w][mi];
        float4 rr = rec[mb + mi];
        double lpd = 0.0;
        if (mb + mi < Mv) {
            float xv = rr.x, yv = rr.y, Cl2 = rr.w;
            float ly  = flog2(yv) * LN2_F;
            float y2s = yv * yv * inv_sn2;
            float lp12 = base12 + ly - y2s + Qc + LN2_F * (Cl2 + flog2(sm));
            float e1 = xv - I1, e2 = xv - I2;
            float base_i = K + 2.0f * ly - y2s;
            float lp1 = base_i - c2n * e1 * e1;
            float lp2 = base_i - c2n * e2 * e2;
            float b0 = lw0 + lp1, b1 = lw1 + lp2, b2 = lw2 + lp12;
            float mm = fmaxf(b0, fmaxf(b1, b2));
            float lp = mm + LN2_F * flog2(fexp2((b0 - mm) * L2E)
                      + fexp2((b1 - mm) * L2E) + fexp2((b2 - mm) * L2E));
            lpd = (double)lp;
        }
#pragma unroll
        for (int o = 32; o > 0; o >>= 1) lpd += __shfl_xor(lpd, o, 64);
        if (lane == 0) sred[wv] = lpd;
    }
    __syncthreads();
    if (tid == 0) partials[blockIdx.x] = (sred[0] + sred[1]) + (sred[2] + sred[3]);
}

// ---------------- final reduction ----------------
__global__ void reduce_kernel(const double* __restrict__ partials, float* __restrict__ out) {
    __shared__ double red[256];
    double a = 0.0;
    for (int i = threadIdx.x; i < MAIN_BLOCKS; i += 256) a += partials[i];
    red[threadIdx.x] = a;
    __syncthreads();
    for (int s = 128; s > 0; s >>= 1) {
        if (threadIdx.x < s) red[threadIdx.x] += red[threadIdx.x + s];
        __syncthreads();
    }
    if (threadIdx.x == 0) out[0] = (float)(-red[0]);
}

extern "C" void kernel_launch(void* const* d_in, const int* in_sizes, int n_in,
                              void* d_out, int out_size, void* d_ws, size_t ws_size,
                              hipStream_t stream) {
    const float* x   = (const float*)d_in[0];
    const float* y   = (const float*)d_in[1];
    const float* k_u = (const float*)d_in[2];
    const float* sb  = (const float*)d_in[3];
    const float* sn  = (const float*)d_in[4];
    const float* I1  = (const float*)d_in[5];
    const float* I2  = (const float*)d_in[6];
    const float* w1  = (const float*)d_in[7];
    const float* w2  = (const float*)d_in[8];
    const float* w12 = (const float*)d_in[9];
    int Mv = in_sizes[0];

    char* ws = (char*)d_ws;
    float4* rec      = (float4*)ws;                              // 4 MB
    double* partials = (double*)(ws + (size_t)PREP_BLOCKS * NTHR_PREP * 16);
    float*  nPp      = (float*)((char*)partials + MAIN_BLOCKS * 8);
    float*  nT       = nPp + N_MC;
    float*  nB       = nT + N_MC;

    prep_kernel<<<PREP_BLOCKS, NTHR_PREP, 0, stream>>>(x, y, k_u, sb, sn, I1, I2,
                                                       rec, nPp, nT, nB, Mv);
    main_kernel<<<MAIN_BLOCKS, CB, 0, stream>>>(rec, nPp, nT, nB, sn, I1, I2,
                                                w1, w2, w12, partials, Mv);
    reduce_kernel<<<1, 256, 0, stream>>>(partials, (float*)d_out);
}